// Round 2
// baseline (1765.625 us; speedup 1.0000x reference)
//
#include <hip/hip_runtime.h>
#include <hip/hip_bf16.h>
#include <math.h>

#define TM 128   // edges per kron-GEMM tile (must stay 128: fixup uses >>7)

typedef __attribute__((ext_vector_type(8))) short bfrag;   // 8 bf16 (4 VGPRs)
typedef __attribute__((ext_vector_type(4))) float cfrag;   // 4 fp32 acc

__device__ __forceinline__ ushort f2bf(float f) {
    __hip_bfloat16 h = __float2bfloat16(f);
    return *(ushort*)&h;
}
__device__ __forceinline__ float bf2f(ushort u) {
    __hip_bfloat16 h;
    *(ushort*)&h = u;
    return __bfloat162float(h);
}

// ---------------------------------------------------------------- helpers
__device__ __forceinline__ void blockSum2(float& s1, float& s2, float* red) {
    #pragma unroll
    for (int off = 32; off > 0; off >>= 1) {
        s1 += __shfl_xor(s1, off);
        s2 += __shfl_xor(s2, off);
    }
    int lane = threadIdx.x & 63, wid = threadIdx.x >> 6;
    if (lane == 0) { red[wid] = s1; red[4 + wid] = s2; }
    __syncthreads();
    s1 = red[0] + red[1] + red[2] + red[3];
    s2 = red[4] + red[5] + red[6] + red[7];
}

__device__ __forceinline__ float sigmoidf(float x) { return 1.0f / (1.0f + expf(-x)); }

// ---------------------------------------------------------------- bf16 cast
__global__ __launch_bounds__(256) void cast_bf16_kernel(
    const float* __restrict__ x, ushort* __restrict__ y, int n)
{
    int i = (blockIdx.x * 256 + threadIdx.x) * 4;
    if (i < n) {
        float4 v = *(const float4*)(x + i);
        ushort4 o;
        o.x = f2bf(v.x); o.y = f2bf(v.y); o.z = f2bf(v.z); o.w = f2bf(v.w);
        *(ushort4*)(y + i) = o;
    }
}

// ---------------------------------------------------------------- weight prep (bf16 B^T layouts)
__global__ __launch_bounds__(256) void prep_w_kernel(
    const float* __restrict__ Wn, const float* __restrict__ Wih,
    const float* __restrict__ Whh, const float* __restrict__ Wc,
    const float* __restrict__ b_ih, const float* __restrict__ b_hh,
    const float* __restrict__ Wp, const float* __restrict__ bp,
    const float* __restrict__ Wk,
    ushort* __restrict__ BTn, ushort* __restrict__ BTrz,
    ushort* __restrict__ BTin, ushort* __restrict__ BThn,
    ushort* __restrict__ BTc, float* __restrict__ bias_rz,
    ushort* __restrict__ BTp, float* __restrict__ bp_pad,
    ushort* __restrict__ Wkt)
{
    int id = blockIdx.x * 256 + threadIdx.x;
    if (id < 262144) {
        int n = id >> 9, k = id & 511;
        float v = (k < 256) ? Wih[n * 256 + k] : Whh[n * 256 + k - 256];
        BTrz[id] = f2bf(v);
    } else if (id < 327680) {
        int j = id - 262144; int n = j >> 8, k = j & 255;
        BTin[j] = f2bf(Wih[(512 + n) * 256 + k]);
    } else if (id < 393216) {
        int j = id - 327680; int n = j >> 8, k = j & 255;
        BThn[j] = f2bf(Whh[(512 + n) * 256 + k]);
    } else if (id < 458752) {
        int j = id - 393216; int n = j >> 8, k = j & 255;
        BTn[j] = f2bf(Wn[k * 256 + n]);
    } else if (id < 589824) {
        int j = id - 458752; int n = j >> 9, k = j & 511;
        BTc[j] = f2bf(Wc[k * 256 + n]);
    } else if (id < 590336) {
        int n = id - 589824;
        bias_rz[n] = b_ih[n] + b_hh[n];
    } else if (id < 623104) {
        int j = id - 590336; int n = j >> 8, k = j & 255;
        BTp[j] = f2bf((n < 20) ? Wp[k * 20 + n] : 0.f);
    } else if (id < 623232) {
        int n = id - 623104;
        bp_pad[n] = (n < 20) ? bp[n] : 0.f;
    } else if (id < 737920) {
        // Wkt[o][c] = Wk[c][o], bf16, c padded 400->448 with zeros
        int j = id - 623232; int o = j / 448; int c = j - o * 448;
        Wkt[j] = f2bf((c < 400) ? Wk[(size_t)c * 256 + o] : 0.f);
    }
}

// ---------------------------------------------------------------- generic bf16 MFMA GEMM (128x128, BK=64)
__global__ __launch_bounds__(256) void mfma_gemm_kernel(
    const ushort* __restrict__ A1, const ushort* __restrict__ A2, int ksplit, int lda,
    const ushort* __restrict__ B, const float* __restrict__ bias,
    void* __restrict__ Cout, int store_bf16,
    int M, int N, int K, int ldc)
{
    __shared__ ushort As[128 * 64];
    __shared__ ushort Bs[128 * 64];
    int t = threadIdx.x;
    int m0 = blockIdx.x * 128, n0 = blockIdx.y * 128;
    int w = t >> 6, lane = t & 63;
    int q = lane >> 4, r = lane & 15;
    int wm = (w & 1) * 64, wn = (w >> 1) * 64;

    cfrag acc[4][4] = {};

    int srow_base = t >> 3;
    int skc = t & 7;

    for (int k0 = 0; k0 < K; k0 += 64) {
        const ushort* Ap; int kb;
        if (k0 < ksplit) { Ap = A1; kb = k0; } else { Ap = A2; kb = k0 - ksplit; }
        int4 av[4], bv[4];
        #pragma unroll
        for (int i = 0; i < 4; ++i) {
            int row = i * 32 + srow_base;
            int grow = m0 + row;
            av[i] = make_int4(0, 0, 0, 0);
            if (grow < M) av[i] = *(const int4*)(Ap + (size_t)grow * lda + kb + skc * 8);
            bv[i] = *(const int4*)(B + (size_t)(n0 + row) * K + k0 + skc * 8);
        }
        __syncthreads();
        #pragma unroll
        for (int i = 0; i < 4; ++i) {
            int row = i * 32 + srow_base;
            int off = row * 64 + ((skc ^ (row & 7)) * 8);
            *(int4*)&As[off] = av[i];
            *(int4*)&Bs[off] = bv[i];
        }
        __syncthreads();
        #pragma unroll
        for (int s = 0; s < 2; ++s) {
            bfrag af[4], bfr[4];
            int kc = s * 4 + q;
            #pragma unroll
            for (int mi = 0; mi < 4; ++mi) {
                int arow = wm + mi * 16 + r;
                af[mi] = *(const bfrag*)&As[arow * 64 + ((kc ^ (arow & 7)) * 8)];
            }
            #pragma unroll
            for (int ni = 0; ni < 4; ++ni) {
                int brow = wn + ni * 16 + r;
                bfr[ni] = *(const bfrag*)&Bs[brow * 64 + ((kc ^ (brow & 7)) * 8)];
            }
            #pragma unroll
            for (int mi = 0; mi < 4; ++mi)
                #pragma unroll
                for (int ni = 0; ni < 4; ++ni)
                    acc[mi][ni] = __builtin_amdgcn_mfma_f32_16x16x32_bf16(
                        af[mi], bfr[ni], acc[mi][ni], 0, 0, 0);
        }
    }

    float bvld[4];
    #pragma unroll
    for (int ni = 0; ni < 4; ++ni) bvld[ni] = bias[n0 + wn + ni * 16 + r];
    #pragma unroll
    for (int mi = 0; mi < 4; ++mi) {
        #pragma unroll
        for (int v = 0; v < 4; ++v) {
            int grow = m0 + wm + mi * 16 + q * 4 + v;
            if (grow >= M) continue;
            #pragma unroll
            for (int ni = 0; ni < 4; ++ni) {
                int gcol = n0 + wn + ni * 16 + r;
                if (gcol >= N) continue;
                float val = acc[mi][ni][v] + bvld[ni];
                if (store_bf16) ((ushort*)Cout)[(size_t)grow * ldc + gcol] = f2bf(val);
                else            ((float*)Cout)[(size_t)grow * ldc + gcol] = val;
            }
        }
    }
}

// ---------------------------------------------------------------- LN(20)+relu on npj32 [V,32] -> npj [V,20]
__global__ __launch_bounds__(256) void ln20_kernel(
    const float* __restrict__ npj32, const float* __restrict__ gp,
    const float* __restrict__ betap, float* __restrict__ npj, int V)
{
    int wid = threadIdx.x >> 6, j = threadIdx.x & 63;
    int v = blockIdx.x * 4 + wid;
    if (v >= V) return;
    float acc = (j < 20) ? npj32[(size_t)v * 32 + j] : 0.f;
    float s1 = acc, s2 = acc * acc;
    #pragma unroll
    for (int off = 32; off > 0; off >>= 1) {
        s1 += __shfl_xor(s1, off);
        s2 += __shfl_xor(s2, off);
    }
    float mu = s1 * (1.0f / 20.0f);
    float var = s2 * (1.0f / 20.0f) - mu * mu;
    if (j < 20) {
        float y = (acc - mu) * rsqrtf(var + 1e-5f) * gp[j] + betap[j];
        npj[(size_t)v * 20 + j] = fmaxf(y, 0.f);
    }
}

// ---------------------------------------------------------------- CSR build
__global__ __launch_bounds__(256) void deg_kernel(const int* __restrict__ dst, int* __restrict__ deg, int E) {
    int e = blockIdx.x * 256 + threadIdx.x;
    if (e < E) atomicAdd(&deg[dst[e]], 1);
}

__global__ __launch_bounds__(1024) void scan_kernel(const int* __restrict__ deg, int* __restrict__ row, int V) {
    __shared__ int wsum[16];
    __shared__ int carry_sh;
    int t = threadIdx.x, lane = t & 63, wid = t >> 6;
    if (t == 0) carry_sh = 0;
    __syncthreads();
    for (int base = 0; base < V; base += 1024) {
        int i = base + t;
        int val = (i < V) ? deg[i] : 0;
        #pragma unroll
        for (int s = 1; s < 64; s <<= 1) {
            int n = __shfl_up(val, s);
            if (lane >= s) val += n;
        }
        if (lane == 63) wsum[wid] = val;
        __syncthreads();
        if (wid == 0) {
            int x = (lane < 16) ? wsum[lane] : 0;
            #pragma unroll
            for (int s = 1; s < 16; s <<= 1) {
                int n = __shfl_up(x, s);
                if (lane >= s) x += n;
            }
            if (lane < 16) wsum[lane] = x;
        }
        __syncthreads();
        int wprefix = (wid > 0) ? wsum[wid - 1] : 0;
        int c = carry_sh;
        int incl = c + wprefix + val;
        if (i < V) row[i + 1] = incl;
        __syncthreads();
        if (t == 1023) carry_sh = incl;
    }
    if (t == 0) row[0] = 0;
}

__global__ __launch_bounds__(256) void scatter_kernel(
    const int* __restrict__ dst, const int* __restrict__ row,
    int* __restrict__ cnt, int* __restrict__ eorder, int E)
{
    int e = blockIdx.x * 256 + threadIdx.x;
    if (e < E) {
        int d = dst[e];
        int pos = row[d] + atomicAdd(&cnt[d], 1);
        eorder[pos] = e;
    }
}

// ---------------------------------------------------------------- per-node edge-logit projections
__global__ __launch_bounds__(256) void nodeproj_kernel(
    const float* __restrict__ nf, const float* __restrict__ We,
    float* __restrict__ pd, float* __restrict__ ps, int V)
{
    int wid = threadIdx.x >> 6, lane = threadIdx.x & 63;
    int v = blockIdx.x * 4 + wid;
    if (v >= V) return;
    const float* row = nf + (size_t)v * 256;
    int i = lane * 4;
    float4 x  = *(const float4*)(row + i);
    float4 wd = *(const float4*)(We + i);
    float4 wsv = *(const float4*)(We + 256 + i);
    float sd = x.x * wd.x + x.y * wd.y + x.z * wd.z + x.w * wd.w;
    float ss = x.x * wsv.x + x.y * wsv.y + x.z * wsv.z + x.w * wsv.w;
    #pragma unroll
    for (int off = 32; off > 0; off >>= 1) {
        sd += __shfl_xor(sd, off);
        ss += __shfl_xor(ss, off);
    }
    if (lane == 0) { pd[v] = sd; ps[v] = ss; }
}

// ---------------------------------------------------------------- edge prep (eorder order)
__global__ __launch_bounds__(256) void edgeprep_kernel(
    const int* __restrict__ eorder, const int* __restrict__ src, const int* __restrict__ dst,
    const float* __restrict__ pd, const float* __restrict__ ps, const float* __restrict__ be,
    float* __restrict__ logitOrd, int* __restrict__ srcOrd, int* __restrict__ dstOrd, int E)
{
    int p = blockIdx.x * 256 + threadIdx.x;
    if (p < E) {
        int e = eorder[p];
        int s = src[e], d = dst[e];
        srcOrd[p] = s;
        dstOrd[p] = d;
        logitOrd[p] = fmaxf(pd[d] + ps[s] + be[0], 0.f);
    }
}

// ---------------------------------------------------------------- kron branch as fused MFMA GEMM
// Y[E,256] = A[E,448] @ Wkt^T where A[e, a*20+k] = npj[src_e][a]*npj[dst_e][k] (cols>=400 zero),
// generated on the fly into LDS.  BN=256 covers the full LN row -> per-edge LN fused via
// cross-wave LDS reduce.  Segment-sum by dst fused in epilogue: per-column run scan over the
// 128-edge tile (edges CSR-sorted by dst); interior dst -> direct bf16 store to acat,
// tile-boundary dst -> f32 atomicAdd into kron_acc (fixed up by fixkron_kernel).
__global__ __launch_bounds__(512) void krongemm_kernel(
    const float* __restrict__ npj, const int* __restrict__ srcOrd,
    const int* __restrict__ dstOrd, const int* __restrict__ rowPtr,
    const ushort* __restrict__ Wkt, const float* __restrict__ bk,
    const float* __restrict__ gkv, const float* __restrict__ betak,
    ushort* __restrict__ acat, float* __restrict__ kron_acc, int E)
{
    // LDS carve (total 65032 B):
    __shared__ __align__(16) char smem[65056];
    ushort* As   = (ushort*)(smem);            // [128][64] swizzled, 16384 B
    ushort* Bs   = (ushort*)(smem + 16384);    // [256][64] swizzled, 32768 B
    ushort* sSrc = (ushort*)(smem + 49152);    // [128][20] bf16, 5120 B
    ushort* sDst = (ushort*)(smem + 54272);    // [128][20] bf16, 5120 B
    int*    sDid = (int*)(smem + 59392);       // [128], 512 B
    float*  red  = (float*)(smem + 59904);     // [4][128][2], 4096 B
    float*  red2 = (float*)(smem + 64000);     // [128][2] (mu,rs), 1024 B
    int*    flags= (int*)(smem + 65024);       // [2]
    ushort* Ys   = (ushort*)(smem);            // epilogue overlay: [128 cols][132] = 33792 B

    int t = threadIdx.x;
    int w = t >> 6, lane = t & 63;
    int q = lane >> 4, r = lane & 15;
    int wm = (w & 1) * 64, wn = (w >> 1) * 64;

    int p0 = blockIdx.x * TM;
    int n = E - p0; if (n > TM) n = TM;

    // ---- stage per-tile npj rows (bf16) + dst ids + boundary flags
    for (int idx = t; idx < TM * 20; idx += 512) {
        int le = idx / 20; int j = idx - le * 20;
        int p = p0 + le;
        float vs = 0.f, vd = 0.f;
        if (p < E) {
            vs = npj[(size_t)srcOrd[p] * 20 + j];
            vd = npj[(size_t)dstOrd[p] * 20 + j];
        }
        sSrc[idx] = f2bf(vs);
        sDst[idx] = f2bf(vd);
    }
    if (t < TM) sDid[t] = (p0 + t < E) ? dstOrd[p0 + t] : -1;
    if (t == 0) {
        int d0 = dstOrd[p0];
        int dl = dstOrd[p0 + n - 1];
        flags[0] = (rowPtr[d0] == p0) ? 1 : 0;
        flags[1] = (rowPtr[dl + 1] == p0 + n) ? 1 : 0;
    }
    __syncthreads();

    cfrag acc[4][4] = {};

    int arow = t >> 2;           // A-gen row (0..127)
    int jgrp = t & 3;            // 16-col group within BK

    int brow = t >> 1;           // Bs row (0..255)
    int bh = t & 1;              // half of BK

    for (int k0 = 0; k0 < 448; k0 += 64) {
        // Bs global loads (reg-staged)
        int4 bload[4];
        #pragma unroll
        for (int i = 0; i < 4; ++i)
            bload[i] = *(const int4*)(Wkt + (size_t)brow * 448 + k0 + (bh * 4 + i) * 8);

        // A-gen: 16 cols of one row; col = k0 + jgrp*16 + jj; a = col/20 (<=1 boundary in span)
        int c0 = k0 + jgrp * 16;
        int a0 = c0 / 20;
        int sw = a0 * 20 + 20;
        float sA = (a0 < 20) ? bf2f(sSrc[arow * 20 + a0]) : 0.f;
        float sB = (a0 + 1 < 20) ? bf2f(sSrc[arow * 20 + a0 + 1]) : 0.f;
        ushort ou[16];
        #pragma unroll
        for (int jj = 0; jj < 16; ++jj) {
            int col = c0 + jj;
            bool hi = (col >= sw);
            int aa = hi ? (a0 + 1) : a0;
            int k = col - aa * 20;
            float dv = bf2f(sDst[arow * 20 + k]);   // k always in [0,20)
            float sv = hi ? sB : sA;
            float pv = (col < 400) ? (sv * dv) : 0.f;
            ou[jj] = f2bf(pv);
        }
        int4 alo, ahi;
        alo.x = (int)ou[0]  | ((int)ou[1]  << 16);
        alo.y = (int)ou[2]  | ((int)ou[3]  << 16);
        alo.z = (int)ou[4]  | ((int)ou[5]  << 16);
        alo.w = (int)ou[6]  | ((int)ou[7]  << 16);
        ahi.x = (int)ou[8]  | ((int)ou[9]  << 16);
        ahi.y = (int)ou[10] | ((int)ou[11] << 16);
        ahi.z = (int)ou[12] | ((int)ou[13] << 16);
        ahi.w = (int)ou[14] | ((int)ou[15] << 16);
        int g0 = jgrp * 2;

        __syncthreads();   // previous MFMA reads of As/Bs done
        *(int4*)&As[arow * 64 + (((g0)     ^ (arow & 7)) << 3)] = alo;
        *(int4*)&As[arow * 64 + (((g0 + 1) ^ (arow & 7)) << 3)] = ahi;
        #pragma unroll
        for (int i = 0; i < 4; ++i) {
            int kcg = bh * 4 + i;
            *(int4*)&Bs[brow * 64 + ((kcg ^ (brow & 7)) << 3)] = bload[i];
        }
        __syncthreads();

        #pragma unroll
        for (int s = 0; s < 2; ++s) {
            bfrag af[4], bfr[4];
            int kc = s * 4 + q;
            #pragma unroll
            for (int mi = 0; mi < 4; ++mi) {
                int ar = wm + mi * 16 + r;
                af[mi] = *(const bfrag*)&As[ar * 64 + ((kc ^ (ar & 7)) * 8)];
            }
            #pragma unroll
            for (int ni = 0; ni < 4; ++ni) {
                int br = wn + ni * 16 + r;
                bfr[ni] = *(const bfrag*)&Bs[br * 64 + ((kc ^ (br & 7)) * 8)];
            }
            #pragma unroll
            for (int mi = 0; mi < 4; ++mi)
                #pragma unroll
                for (int ni = 0; ni < 4; ++ni)
                    acc[mi][ni] = __builtin_amdgcn_mfma_f32_16x16x32_bf16(
                        af[mi], bfr[ni], acc[mi][ni], 0, 0, 0);
        }
    }

    // ---- epilogue: bias, LN stats (cross-wave), LN+relu, fused segment-sum
    float bv[4], gk4[4], bt4[4];
    #pragma unroll
    for (int ni = 0; ni < 4; ++ni) {
        int col = wn + ni * 16 + r;
        bv[ni] = bk[col];
        gk4[ni] = gkv[col];
        bt4[ni] = betak[col];
    }

    int wnIdx = w >> 1;
    #pragma unroll
    for (int mi = 0; mi < 4; ++mi) {
        #pragma unroll
        for (int v = 0; v < 4; ++v) {
            float s1 = 0.f, s2 = 0.f;
            #pragma unroll
            for (int ni = 0; ni < 4; ++ni) {
                float y = acc[mi][ni][v] + bv[ni];
                s1 += y; s2 += y * y;
            }
            s1 += __shfl_xor(s1, 1); s2 += __shfl_xor(s2, 1);
            s1 += __shfl_xor(s1, 2); s2 += __shfl_xor(s2, 2);
            s1 += __shfl_xor(s1, 4); s2 += __shfl_xor(s2, 4);
            s1 += __shfl_xor(s1, 8); s2 += __shfl_xor(s2, 8);
            if (r == 0) {
                int rowL = wm + mi * 16 + q * 4 + v;
                red[(wnIdx * 128 + rowL) * 2 + 0] = s1;
                red[(wnIdx * 128 + rowL) * 2 + 1] = s2;
            }
        }
    }
    __syncthreads();
    if (t < 128) {
        float S1 = red[(0 * 128 + t) * 2] + red[(1 * 128 + t) * 2]
                 + red[(2 * 128 + t) * 2] + red[(3 * 128 + t) * 2];
        float S2 = red[(0 * 128 + t) * 2 + 1] + red[(1 * 128 + t) * 2 + 1]
                 + red[(2 * 128 + t) * 2 + 1] + red[(3 * 128 + t) * 2 + 1];
        float mu = S1 * (1.0f / 256.0f);
        float var = S2 * (1.0f / 256.0f) - mu * mu;
        red2[t * 2 + 0] = mu;
        red2[t * 2 + 1] = rsqrtf(var + 1e-5f);
    }
    __syncthreads();

    int fFirst = flags[0], fLast = flags[1];

    // two column-half passes (Ys overlay = 33792 B, fits over As+Bs)
    #pragma unroll
    for (int h = 0; h < 2; ++h) {
        if ((wn >> 7) == h) {
            #pragma unroll
            for (int mi = 0; mi < 4; ++mi) {
                int rowBase = wm + mi * 16 + q * 4;
                float4 m01 = *(const float4*)&red2[(rowBase) * 2];      // mu0,rs0,mu1,rs1
                float4 m23 = *(const float4*)&red2[(rowBase + 2) * 2];  // mu2,rs2,mu3,rs3
                #pragma unroll
                for (int ni = 0; ni < 4; ++ni) {
                    int colL = (wn & 127) + ni * 16 + r;
                    float y0 = fmaxf((acc[mi][ni][0] + bv[ni] - m01.x) * m01.y * gk4[ni] + bt4[ni], 0.f);
                    float y1 = fmaxf((acc[mi][ni][1] + bv[ni] - m01.z) * m01.w * gk4[ni] + bt4[ni], 0.f);
                    float y2 = fmaxf((acc[mi][ni][2] + bv[ni] - m23.x) * m23.y * gk4[ni] + bt4[ni], 0.f);
                    float y3 = fmaxf((acc[mi][ni][3] + bv[ni] - m23.z) * m23.w * gk4[ni] + bt4[ni], 0.f);
                    int2 pk;
                    pk.x = (int)f2bf(y0) | ((int)f2bf(y1) << 16);
                    pk.y = (int)f2bf(y2) | ((int)f2bf(y3) << 16);
                    *(int2*)&Ys[colL * 132 + rowBase] = pk;
                }
            }
        }
        __syncthreads();
        if (t < 128) {
            int colG = h * 128 + t;
            float accum = 0.f;
            int cur = sDid[0];
            int runStart = 0;
            for (int rw = 0; rw < n; rw += 4) {
                int2 pk = *(const int2*)&Ys[t * 132 + rw];
                ushort vals[4];
                vals[0] = (ushort)(pk.x & 0xffff);
                vals[1] = (ushort)((unsigned)pk.x >> 16);
                vals[2] = (ushort)(pk.y & 0xffff);
                vals[3] = (ushort)((unsigned)pk.y >> 16);
                #pragma unroll
                for (int j = 0; j < 4; ++j) {
                    int row = rw + j;
                    if (row >= n) break;
                    int d = sDid[row];
                    if (d != cur) {
                        // flush run [runStart, row-1] (ended mid-tile -> end is genuine)
                        if (cur >= 0) {
                            bool inter = (runStart > 0 || fFirst);
                            if (inter) acat[(size_t)cur * 512 + 256 + colG] = f2bf(accum);
                            else       atomicAdd(&kron_acc[(size_t)cur * 256 + colG], accum);
                        }
                        cur = d; runStart = row; accum = 0.f;
                    }
                    accum += bf2f(vals[j]);
                }
            }
            if (cur >= 0) {
                bool inter = (runStart > 0 || fFirst) && fLast;
                if (inter) acat[(size_t)cur * 512 + 256 + colG] = f2bf(accum);
                else       atomicAdd(&kron_acc[(size_t)cur * 256 + colG], accum);
            }
        }
        __syncthreads();
    }
}

// ---------------------------------------------------------------- fixup for tile-split / empty dst
__global__ __launch_bounds__(256) void fixkron_kernel(
    const int* __restrict__ rowp, const float* __restrict__ kron_acc,
    ushort* __restrict__ acat, int V)
{
    int v = blockIdx.x, t = threadIdx.x;
    int r0 = rowp[v], r1 = rowp[v + 1];
    if (r0 == r1) {
        acat[(size_t)v * 512 + 256 + t] = f2bf(0.f);
    } else if ((r0 >> 7) != ((r1 - 1) >> 7)) {
        acat[(size_t)v * 512 + 256 + t] = f2bf(kron_acc[(size_t)v * 256 + t]);
    }
}

// ---------------------------------------------------------------- attention stats per dst (linear reads)
__global__ __launch_bounds__(256) void att_kernel(
    const float* __restrict__ logitOrd, const int* __restrict__ rowPtr,
    float* __restrict__ mArr, float* __restrict__ invArr, int V)
{
    int wid = threadIdx.x >> 6, lane = threadIdx.x & 63;
    int v = blockIdx.x * 4 + wid;
    if (v >= V) return;
    int e0 = rowPtr[v], e1 = rowPtr[v + 1];
    float m = -1e30f;
    for (int p = e0 + lane; p < e1; p += 64) m = fmaxf(m, logitOrd[p]);
    #pragma unroll
    for (int off = 32; off > 0; off >>= 1) m = fmaxf(m, __shfl_xor(m, off));
    float d = 0.f;
    for (int p = e0 + lane; p < e1; p += 64) d += expf(logitOrd[p] - m);
    #pragma unroll
    for (int off = 32; off > 0; off >>= 1) d += __shfl_xor(d, off);
    if (lane == 0) {
        mArr[v] = m;
        invArr[v] = (e1 > e0) ? (1.0f / d) : 0.f;
    }
}

// ---------------------------------------------------------------- weighted context (bf16 hv, unroll x4)
__global__ __launch_bounds__(256) void ctx_kernel(
    const ushort* __restrict__ hv_bf, const float* __restrict__ logitOrd,
    const float* __restrict__ mArr, const float* __restrict__ invArr,
    const int* __restrict__ srcOrd, const int* __restrict__ rowPtr,
    ushort* __restrict__ ctx_bf, int V)
{
    int v = blockIdx.x;
    int t = threadIdx.x;
    int e0 = rowPtr[v], e1 = rowPtr[v + 1];
    float m = mArr[v], inv = invArr[v];
    float acc = 0.f;
    int p = e0;
    for (; p + 3 < e1; p += 4) {
        int s0 = srcOrd[p], s1 = srcOrd[p + 1], s2 = srcOrd[p + 2], s3 = srcOrd[p + 3];
        float w0 = expf(logitOrd[p] - m) * inv;
        float w1 = expf(logitOrd[p + 1] - m) * inv;
        float w2 = expf(logitOrd[p + 2] - m) * inv;
        float w3 = expf(logitOrd[p + 3] - m) * inv;
        float h0 = bf2f(hv_bf[(size_t)s0 * 256 + t]);
        float h1 = bf2f(hv_bf[(size_t)s1 * 256 + t]);
        float h2 = bf2f(hv_bf[(size_t)s2 * 256 + t]);
        float h3 = bf2f(hv_bf[(size_t)s3 * 256 + t]);
        acc += w0 * h0 + w1 * h1 + w2 * h2 + w3 * h3;
    }
    for (; p < e1; ++p) {
        float wgt = expf(logitOrd[p] - m) * inv;
        acc += wgt * bf2f(hv_bf[(size_t)srcOrd[p] * 256 + t]);
    }
    ctx_bf[(size_t)v * 256 + t] = f2bf(fmaxf(acc, 0.f));
}

// ---------------------------------------------------------------- GRU gates + LN -> bf16 into acat[:,0:256]
__global__ __launch_bounds__(256) void gru_ln_kernel(
    const ushort* __restrict__ rz, const ushort* __restrict__ inb,
    const ushort* __restrict__ hnb, const float* __restrict__ nf,
    const float* __restrict__ g_ln, const float* __restrict__ b_ln,
    ushort* __restrict__ acat, int V)
{
    __shared__ float red[8];
    int v = blockIdx.x, t = threadIdx.x;
    float r = sigmoidf(bf2f(rz[(size_t)v * 512 + t]));
    float z = sigmoidf(bf2f(rz[(size_t)v * 512 + 256 + t]));
    float n = tanhf(bf2f(inb[(size_t)v * 256 + t]) + r * bf2f(hnb[(size_t)v * 256 + t]));
    float h = (1.f - z) * n + z * nf[(size_t)v * 256 + t];
    float x = fmaxf(h, 0.f);
    float s1 = x, s2 = x * x;
    blockSum2(s1, s2, red);
    float mu = s1 * (1.0f / 256.0f);
    float var = s2 * (1.0f / 256.0f) - mu * mu;
    float y = (x - mu) * rsqrtf(var + 1e-5f) * g_ln[t] + b_ln[t];
    acat[(size_t)v * 512 + t] = f2bf(y);
}

// ---------------------------------------------------------------- row LayerNorm (optional relu)
__global__ __launch_bounds__(256) void ln_kernel(
    const float* __restrict__ in, float* __restrict__ out,
    const float* __restrict__ g, const float* __restrict__ b, int relu_after)
{
    __shared__ float red[8];
    int v = blockIdx.x, t = threadIdx.x;
    float x = in[(size_t)v * 256 + t];
    float s1 = x, s2 = x * x;
    blockSum2(s1, s2, red);
    float mu = s1 * (1.0f / 256.0f);
    float var = s2 * (1.0f / 256.0f) - mu * mu;
    float y = (x - mu) * rsqrtf(var + 1e-5f) * g[t] + b[t];
    if (relu_after) y = fmaxf(y, 0.f);
    out[(size_t)v * 256 + t] = y;
}

// ---------------------------------------------------------------- launcher
extern "C" void kernel_launch(void* const* d_in, const int* in_sizes, int n_in,
                              void* d_out, int out_size, void* d_ws, size_t ws_size,
                              hipStream_t stream)
{
    const float* nf    = (const float*)d_in[0];
    const int*   src   = (const int*)d_in[1];
    const int*   dst   = (const int*)d_in[2];
    const float* Wp    = (const float*)d_in[3];
    const float* bp    = (const float*)d_in[4];
    const float* gp    = (const float*)d_in[5];
    const float* betap = (const float*)d_in[6];
    const float* Wk    = (const float*)d_in[7];
    const float* bk    = (const float*)d_in[8];
    const float* gk    = (const float*)d_in[9];
    const float* betak = (const float*)d_in[10];
    const float* We    = (const float*)d_in[11];
    const float* be    = (const float*)d_in[12];
    const float* Wn    = (const float*)d_in[13];
    const float* bn    = (const float*)d_in[14];
    const float* W_ih  = (const float*)d_in[15];
    const float* W_hh  = (const float*)d_in[16];
    const float* b_ih  = (const float*)d_in[17];
    const float* b_hh  = (const float*)d_in[18];
    const float* g_ln  = (const float*)d_in[19];
    const float* bt_ln = (const float*)d_in[20];
    const float* Wc    = (const float*)d_in[21];
    const float* bc    = (const float*)d_in[22];
    const float* gc    = (const float*)d_in[23];
    const float* betac = (const float*)d_in[24];

    int V = in_sizes[0] / 256;
    int E = in_sizes[1];

    char* w = (char*)d_ws;
    auto alloc = [&](size_t bytes) -> char* {
        char* p = w;
        w += (bytes + 255) & ~(size_t)255;
        return p;
    };
    float*  npj      = (float*)alloc((size_t)V * 20 * 4);
    float*  npj32    = (float*)alloc((size_t)V * 32 * 4);
    ushort* acat     = (ushort*)alloc((size_t)V * 512 * 2);
    ushort* nf_bf    = (ushort*)alloc((size_t)V * 256 * 2);
    ushort* ctx_bf   = (ushort*)alloc((size_t)V * 256 * 2);
    ushort* rz_bf    = (ushort*)alloc((size_t)V * 512 * 2);
    ushort* hv_bf    = rz_bf;  // alias: hv dead before rz GEMM writes
    ushort* in_bf    = (ushort*)alloc((size_t)V * 256 * 2);
    ushort* hn_bf    = (ushort*)alloc((size_t)V * 256 * 2);
    ushort* BTn      = (ushort*)alloc(65536 * 2);
    ushort* BTrz     = (ushort*)alloc(262144 * 2);
    ushort* BTin     = (ushort*)alloc(65536 * 2);
    ushort* BThn     = (ushort*)alloc(65536 * 2);
    ushort* BTc      = (ushort*)alloc(131072 * 2);
    ushort* BTp      = (ushort*)alloc(32768 * 2);
    ushort* Wkt      = (ushort*)alloc(114688 * 2);
    float*  bias_rz  = (float*)alloc(512 * 4);
    float*  bp_pad   = (float*)alloc(128 * 4);
    float*  logitOrd = (float*)alloc((size_t)E * 4);
    int*    srcOrd   = (int*)alloc((size_t)E * 4);
    float*  pd       = (float*)alloc((size_t)V * 4);
    float*  ps       = (float*)alloc((size_t)V * 4);
    float*  mArr     = (float*)alloc((size_t)V * 4);
    float*  invArr   = (float*)alloc((size_t)V * 4);
    int*    deg      = (int*)alloc((size_t)V * 4);
    int*    cnt      = (int*)alloc((size_t)V * 4);
    int*    rowp     = (int*)alloc((size_t)(V + 1) * 4);
    int*    eorder   = (int*)alloc((size_t)E * 4);

    // Aliases (no new workspace):
    //  - dstOrd on npj32: npj32 dead after ln20_kernel; dstOrd written by edgeprep (later).
    //    E*4 = 2.4 MB fits in V*32*4 = 6.4 MB.
    //  - kron_acc on in_bf+hn_bf (contiguous 51.2 MB): consumed by fixkron_kernel BEFORE
    //    the in/hn GEMMs write those buffers.
    int*   dstOrd   = (int*)npj32;
    float* kron_acc = (float*)in_bf;

    hipMemsetAsync(deg, 0, (size_t)V * 4, stream);
    hipMemsetAsync(cnt, 0, (size_t)V * 4, stream);
    hipMemsetAsync(kron_acc, 0, (size_t)V * 256 * 4, stream);

    int mt = (V + 127) / 128;

    cast_bf16_kernel<<<(V * 64 + 255) / 256, 256, 0, stream>>>(nf, nf_bf, V * 256);
    prep_w_kernel<<<(737920 + 255) / 256, 256, 0, stream>>>(
        Wn, W_ih, W_hh, Wc, b_ih, b_hh, Wp, bp, Wk,
        BTn, BTrz, BTin, BThn, BTc, bias_rz, BTp, bp_pad, Wkt);

    // npj32 = nf @ Wp + bp (N padded to 32, via 128-wide tile w/ zero rows)
    mfma_gemm_kernel<<<dim3(mt, 1), 256, 0, stream>>>(
        nf_bf, nf_bf, 256, 256, BTp, bp_pad, npj32, 0, V, 32, 256, 32);
    ln20_kernel<<<(V + 3) / 4, 256, 0, stream>>>(npj32, gp, betap, npj, V);

    deg_kernel<<<(E + 255) / 256, 256, 0, stream>>>(dst, deg, E);
    scan_kernel<<<1, 1024, 0, stream>>>(deg, rowp, V);
    scatter_kernel<<<(E + 255) / 256, 256, 0, stream>>>(dst, rowp, cnt, eorder, E);
    nodeproj_kernel<<<(V + 3) / 4, 256, 0, stream>>>(nf, We, pd, ps, V);
    edgeprep_kernel<<<(E + 255) / 256, 256, 0, stream>>>(
        eorder, src, dst, pd, ps, be, logitOrd, srcOrd, dstOrd, E);

    // hv = nf @ Wn + bn  -> bf16 (aliased on rz_bf; consumed by ctx before rz GEMM)
    mfma_gemm_kernel<<<dim3(mt, 2), 256, 0, stream>>>(
        nf_bf, nf_bf, 256, 256, BTn, bn, hv_bf, 1, V, 256, 256, 256);
    att_kernel<<<(V + 3) / 4, 256, 0, stream>>>(logitOrd, rowp, mArr, invArr, V);
    ctx_kernel<<<V, 256, 0, stream>>>(hv_bf, logitOrd, mArr, invArr, srcOrd, rowp, ctx_bf, V);

    // kron branch: fused on-the-fly GEMM + LN + segment-sum, then fixup for split/empty dst
    int nkb = (E + TM - 1) / TM;
    krongemm_kernel<<<nkb, 512, 0, stream>>>(
        npj, srcOrd, dstOrd, rowp, Wkt, bk, gk, betak, acat, kron_acc, E);
    fixkron_kernel<<<V, 256, 0, stream>>>(rowp, kron_acc, acat, V);

    // rz = [ctx|nf] @ BTrz + (b_ih+b_hh)
    mfma_gemm_kernel<<<dim3(mt, 4), 256, 0, stream>>>(
        ctx_bf, nf_bf, 256, 256, BTrz, bias_rz, rz_bf, 1, V, 512, 512, 512);
    mfma_gemm_kernel<<<dim3(mt, 2), 256, 0, stream>>>(
        ctx_bf, ctx_bf, 256, 256, BTin, b_ih + 512, in_bf, 1, V, 256, 256, 256);
    mfma_gemm_kernel<<<dim3(mt, 2), 256, 0, stream>>>(
        nf_bf, nf_bf, 256, 256, BThn, b_hh + 512, hn_bf, 1, V, 256, 256, 256);

    gru_ln_kernel<<<V, 256, 0, stream>>>(rz_bf, in_bf, hn_bf, nf, g_ln, bt_ln, acat, V);

    mfma_gemm_kernel<<<dim3(mt, 2), 256, 0, stream>>>(
        acat, acat, 512, 512, BTc, bc, (float*)d_out, 0, V, 256, 512, 256);
    ln_kernel<<<V, 256, 0, stream>>>((float*)d_out, (float*)d_out, gc, betac, 1);
}